// Round 3
// baseline (863.644 us; speedup 1.0000x reference)
//
#include <hip/hip_runtime.h>
#include <hip/hip_bf16.h>

#define N_NODES 50000
#define N_EDGES 800000
#define HEADS 4
#define FDIM 256      // HEADS * 64
#define OUT_STRIDE 768
#define SCAN_B 256
#define NBLK ((N_NODES + SCAN_B - 1) / SCAN_B)   // 196 (<= 256, fits single scan block)

// ---------------- helpers ----------------
__device__ __forceinline__ float lrelu(float v) { return v > 0.f ? v : 0.2f * v; }

// ---------------- copy x into d_out[:, 0:256] ----------------
__global__ void k_copy_x(const float* __restrict__ x, float* __restrict__ out) {
    int idx = blockIdx.x * blockDim.x + threadIdx.x;   // N*64 threads (float4 each)
    if (idx >= N_NODES * 64) return;
    int n = idx >> 6, q = idx & 63;
    float4 v = *(const float4*)&x[(size_t)n * FDIM + q * 4];
    *(float4*)&out[(size_t)n * OUT_STRIDE + q * 4] = v;
}

// ---------------- fp32 GEMM: C[M x 256] = A[M x 256 (lda)] @ B[256 x 256] ----------------
// 128x128 tile, BK=16, 256 threads, 2x2 blocks of 4x4 microtile (64 FMA / thread / kk)
#define BM 128
#define BN 128
#define BK 16
#define LDSP (BM + 4)   // +4 floats keeps rows 16B-aligned (132*4 = 33*16)
__global__ __launch_bounds__(256) void k_gemm(const float* __restrict__ A, int lda,
                                              const float* __restrict__ B,
                                              float* __restrict__ C, int M) {
    __shared__ float As[BK][LDSP];
    __shared__ float Bs[BK][LDSP];
    const int tid = threadIdx.x;
    const int tr = tid >> 4;       // 0..15
    const int tc = tid & 15;       // 0..15
    const int brow = blockIdx.x * BM;
    const int bcol = blockIdx.y * BN;
    float acc[2][2][4][4] = {};

    for (int k0 = 0; k0 < 256; k0 += BK) {
        // A tile: 128 rows x 16 k (512 float4 loads, 2/thread), stored k-major
#pragma unroll
        for (int i = 0; i < 2; ++i) {
            int idx = tid + i * 256;          // 0..511
            int row = idx >> 2;               // 0..127
            int kq  = (idx & 3) * 4;          // 0,4,8,12
            int gr = brow + row;
            float4 v = make_float4(0.f, 0.f, 0.f, 0.f);
            if (gr < M) v = *(const float4*)&A[(size_t)gr * lda + k0 + kq];
            As[kq + 0][row] = v.x; As[kq + 1][row] = v.y;
            As[kq + 2][row] = v.z; As[kq + 3][row] = v.w;
        }
        // B tile: 16 k x 128 cols (512 float4 loads, 2/thread)
#pragma unroll
        for (int i = 0; i < 2; ++i) {
            int idx = tid + i * 256;
            int kk  = idx >> 5;               // 0..15
            int col = (idx & 31) * 4;         // 0..124
            *(float4*)&Bs[kk][col] = *(const float4*)&B[(size_t)(k0 + kk) * 256 + bcol + col];
        }
        __syncthreads();
#pragma unroll
        for (int kk = 0; kk < BK; ++kk) {
            float4 a0 = *(const float4*)&As[kk][tr * 4];
            float4 a1 = *(const float4*)&As[kk][64 + tr * 4];
            float4 b0 = *(const float4*)&Bs[kk][tc * 4];
            float4 b1 = *(const float4*)&Bs[kk][64 + tc * 4];
            const float av0[4] = {a0.x, a0.y, a0.z, a0.w};
            const float av1[4] = {a1.x, a1.y, a1.z, a1.w};
            const float bv0[4] = {b0.x, b0.y, b0.z, b0.w};
            const float bv1[4] = {b1.x, b1.y, b1.z, b1.w};
#pragma unroll
            for (int i = 0; i < 4; ++i)
#pragma unroll
                for (int j = 0; j < 4; ++j) {
                    acc[0][0][i][j] += av0[i] * bv0[j];
                    acc[0][1][i][j] += av0[i] * bv1[j];
                    acc[1][0][i][j] += av1[i] * bv0[j];
                    acc[1][1][i][j] += av1[i] * bv1[j];
                }
        }
        __syncthreads();
    }
#pragma unroll
    for (int bi = 0; bi < 2; ++bi)
#pragma unroll
        for (int i = 0; i < 4; ++i) {
            int gr = brow + bi * 64 + tr * 4 + i;
            if (gr >= M) continue;
#pragma unroll
            for (int bj = 0; bj < 2; ++bj) {
                float4 v = make_float4(acc[bi][bj][i][0], acc[bi][bj][i][1],
                                       acc[bi][bj][i][2], acc[bi][bj][i][3]);
                *(float4*)&C[(size_t)gr * 256 + bcol + bj * 64 + tc * 4] = v;
            }
        }
}

// ---------------- el/er: one wave per node ----------------
__global__ void k_el_er(const float* __restrict__ feat,
                        const float* __restrict__ al, const float* __restrict__ ar,
                        float* __restrict__ el, float* __restrict__ er) {
    int gtid = blockIdx.x * blockDim.x + threadIdx.x;
    int node = gtid >> 6;
    int lane = threadIdx.x & 63;
    if (node >= N_NODES) return;
    float4 f = *(const float4*)&feat[(size_t)node * FDIM + lane * 4];
    float4 a = *(const float4*)&al[lane * 4];
    float4 r = *(const float4*)&ar[lane * 4];
    float pl = f.x * a.x + f.y * a.y + f.z * a.z + f.w * a.w;
    float pr = f.x * r.x + f.y * r.y + f.z * r.z + f.w * r.w;
    // reduce within each 16-lane group (lanes 16h..16h+15 cover head h's 64 ch)
#pragma unroll
    for (int off = 8; off >= 1; off >>= 1) {
        pl += __shfl_xor(pl, off, 64);
        pr += __shfl_xor(pr, off, 64);
    }
    if ((lane & 15) == 0) {
        int h = lane >> 4;
        el[node * HEADS + h] = pl;
        er[node * HEADS + h] = pr;
    }
}

// ---------------- CSR build (once per launch; shared by both layers) ----------------
__global__ void k_zero_counts(int* __restrict__ counts) {
    int i = blockIdx.x * blockDim.x + threadIdx.x;
    if (i < N_NODES) counts[i] = 0;
}
__global__ void k_hist(const int* __restrict__ dst, int* __restrict__ counts) {
    int e = blockIdx.x * blockDim.x + threadIdx.x;
    if (e < N_EDGES) atomicAdd(&counts[dst[e]], 1);
}
__global__ void k_scan1(const int* __restrict__ counts, int* __restrict__ excl,
                        int* __restrict__ blocksums) {
    __shared__ int s[SCAN_B];
    int tid = threadIdx.x;
    int i = blockIdx.x * SCAN_B + tid;
    int v = (i < N_NODES) ? counts[i] : 0;
    s[tid] = v;
    __syncthreads();
    for (int off = 1; off < SCAN_B; off <<= 1) {
        int t = (tid >= off) ? s[tid - off] : 0;
        __syncthreads();
        s[tid] += t;
        __syncthreads();
    }
    if (i < N_NODES) excl[i] = s[tid] - v;
    if (tid == SCAN_B - 1) blocksums[blockIdx.x] = s[tid];
}
__global__ void k_scan2(int* __restrict__ blocksums) {   // single block; NBLK <= 256
    __shared__ int s[SCAN_B];
    int tid = threadIdx.x;
    int v = (tid < NBLK) ? blocksums[tid] : 0;
    s[tid] = v;
    __syncthreads();
    for (int off = 1; off < SCAN_B; off <<= 1) {
        int t = (tid >= off) ? s[tid - off] : 0;
        __syncthreads();
        s[tid] += t;
        __syncthreads();
    }
    if (tid < NBLK) blocksums[tid] = s[tid] - v;   // exclusive
}
__global__ void k_scan3(const int* __restrict__ excl, const int* __restrict__ blocksums,
                        int* __restrict__ row_start, int* __restrict__ cursor) {
    int i = blockIdx.x * blockDim.x + threadIdx.x;
    if (i >= N_NODES) return;
    int r = excl[i] + blocksums[i >> 8];
    row_start[i] = r;
    cursor[i] = r;
}
__global__ void k_place(const int* __restrict__ src, const int* __restrict__ dst,
                        int* __restrict__ cursor, int* __restrict__ csr_src) {
    int e = blockIdx.x * blockDim.x + threadIdx.x;
    if (e >= N_EDGES) return;
    int pos = atomicAdd(&cursor[dst[e]], 1);
    csr_src[pos] = src[e];
}

// ---------------- fused edge softmax + aggregate: one wave per dst node ----------------
// Single pass, online softmax: running max m, denom, acc; branch-free rescale.
__global__ void k_gather(const int* __restrict__ row_start, const int* __restrict__ counts,
                         const int* __restrict__ csr_src,
                         const float* __restrict__ feat,
                         const float* __restrict__ el, const float* __restrict__ er,
                         const float* __restrict__ bias,
                         float* __restrict__ out_slice, int apply_elu) {
    int gtid = blockIdx.x * blockDim.x + threadIdx.x;
    int node = gtid >> 6;
    if (node >= N_NODES) return;
    int lane = threadIdx.x & 63;
    int h = lane >> 4;                           // head of this lane's 4 channels
    float4 bv = *(const float4*)&bias[lane * 4];
    int start = row_start[node];
    int cnt = counts[node];
    float4 acc = make_float4(0.f, 0.f, 0.f, 0.f);
    if (cnt > 0) {
        float erd = er[node * HEADS + h];
        float m = -1e30f, denom = 0.f;
        for (int i = 0; i < cnt; ++i) {
            int s = csr_src[start + i];
            float v = lrelu(el[s * HEADS + h] + erd);
            float mn = fmaxf(m, v);
            float scale = __expf(m - mn);        // 1 when no new max
            float ex = __expf(v - mn);
            m = mn;
            denom = denom * scale + ex;
            float4 f = *(const float4*)&feat[(size_t)s * FDIM + lane * 4];
            acc.x = acc.x * scale + ex * f.x;
            acc.y = acc.y * scale + ex * f.y;
            acc.z = acc.z * scale + ex * f.z;
            acc.w = acc.w * scale + ex * f.w;
        }
        float inv = 1.f / denom;
        acc.x = acc.x * inv + bv.x; acc.y = acc.y * inv + bv.y;
        acc.z = acc.z * inv + bv.z; acc.w = acc.w * inv + bv.w;
    } else {
        acc = bv;   // empty segment: message sum is 0, out = bias
    }
    if (apply_elu) {
        acc.x = acc.x > 0.f ? acc.x : expm1f(acc.x);
        acc.y = acc.y > 0.f ? acc.y : expm1f(acc.y);
        acc.z = acc.z > 0.f ? acc.z : expm1f(acc.z);
        acc.w = acc.w > 0.f ? acc.w : expm1f(acc.w);
    }
    *(float4*)&out_slice[(size_t)node * OUT_STRIDE + lane * 4] = acc;
}

// ---------------- per-layer driver ----------------
static void run_layer(const float* in, int lda,
                      const float* W, const float* al, const float* ar, const float* bias,
                      float* out_slice, int apply_elu,
                      const int* row_start, const int* counts, const int* csr_src,
                      float* feat, float* el, float* er, hipStream_t stream) {
    dim3 ggrid((N_NODES + BM - 1) / BM, 256 / BN);
    k_gemm<<<ggrid, 256, 0, stream>>>(in, lda, W, feat, N_NODES);
    k_el_er<<<(N_NODES * 64 + 255) / 256, 256, 0, stream>>>(feat, al, ar, el, er);
    k_gather<<<(N_NODES * 64 + 255) / 256, 256, 0, stream>>>(
        row_start, counts, csr_src, feat, el, er, bias, out_slice, apply_elu);
}

extern "C" void kernel_launch(void* const* d_in, const int* in_sizes, int n_in,
                              void* d_out, int out_size, void* d_ws, size_t ws_size,
                              hipStream_t stream) {
    const float* x   = (const float*)d_in[0];
    const int*   src = (const int*)d_in[1];
    const int*   dst = (const int*)d_in[2];
    const float* W1  = (const float*)d_in[3];
    const float* al1 = (const float*)d_in[4];
    const float* ar1 = (const float*)d_in[5];
    const float* b1  = (const float*)d_in[6];
    const float* W2  = (const float*)d_in[7];
    const float* al2 = (const float*)d_in[8];
    const float* ar2 = (const float*)d_in[9];
    const float* b2  = (const float*)d_in[10];
    float* out = (float*)d_out;

    // workspace carve-up; guard against undersized ws (fail validation, not the GPU)
    size_t need_bytes = ((size_t)N_NODES * FDIM + 2u * N_NODES * HEADS) * 4u  // feat, el, er
                      + ((size_t)4 * N_NODES + 256 + N_EDGES) * 4u;           // csr ints
    if (ws_size < need_bytes) return;

    float* ws        = (float*)d_ws;
    float* feat      = ws;                                    // N*256 floats
    float* el        = feat + (size_t)N_NODES * FDIM;         // N*4
    float* er        = el + N_NODES * HEADS;                  // N*4
    int*   counts    = (int*)(er + N_NODES * HEADS);          // N
    int*   excl      = counts + N_NODES;                      // N
    int*   row_start = excl + N_NODES;                        // N
    int*   cursor    = row_start + N_NODES;                   // N
    int*   blocksums = cursor + N_NODES;                      // 256
    int*   csr_src   = blocksums + 256;                       // E

    // ---- CSR build (shared by both layers) ----
    k_zero_counts<<<(N_NODES + 255) / 256, 256, 0, stream>>>(counts);
    k_hist<<<(N_EDGES + 255) / 256, 256, 0, stream>>>(dst, counts);
    k_scan1<<<NBLK, SCAN_B, 0, stream>>>(counts, excl, blocksums);
    k_scan2<<<1, SCAN_B, 0, stream>>>(blocksums);
    k_scan3<<<(N_NODES + 255) / 256, 256, 0, stream>>>(excl, blocksums, row_start, cursor);
    k_place<<<(N_EDGES + 255) / 256, 256, 0, stream>>>(src, dst, cursor, csr_src);

    // ---- x -> out[:, 0:256] ----
    k_copy_x<<<(N_NODES * 64 + 255) / 256, 256, 0, stream>>>(x, out);

    // ---- layer 1: x -> out[:, 256:512] (ELU) ----
    run_layer(x, FDIM, W1, al1, ar1, b1, out + 256, 1,
              row_start, counts, csr_src, feat, el, er, stream);

    // ---- layer 2: h1 (strided in out) -> out[:, 512:768] ----
    run_layer(out + 256, OUT_STRIDE, W2, al2, ar2, b2, out + 512, 0,
              row_start, counts, csr_src, feat, el, er, stream);
}

// Round 4
// 844.398 us; speedup vs baseline: 1.0228x; 1.0228x over previous
//
#include <hip/hip_runtime.h>
#include <hip/hip_bf16.h>

#define N_NODES 50000
#define N_EDGES 800000
#define HEADS 4
#define FDIM 256      // HEADS * 64
#define OUT_STRIDE 768
#define SCAN_B 256
#define NBLK ((N_NODES + SCAN_B - 1) / SCAN_B)   // 196 (<= 256, fits single scan block)

// ---------------- helpers ----------------
__device__ __forceinline__ float lrelu(float v) { return v > 0.f ? v : 0.2f * v; }

// ---------------- copy x into d_out[:, 0:256] ----------------
__global__ void k_copy_x(const float* __restrict__ x, float* __restrict__ out) {
    int idx = blockIdx.x * blockDim.x + threadIdx.x;   // N*64 threads (float4 each)
    if (idx >= N_NODES * 64) return;
    int n = idx >> 6, q = idx & 63;
    float4 v = *(const float4*)&x[(size_t)n * FDIM + q * 4];
    *(float4*)&out[(size_t)n * OUT_STRIDE + q * 4] = v;
}

// ---------------- fp32 GEMM + fused el/er epilogue ----------------
// C[M x 256] = A[M x 256 (lda)] @ B[256 x 256]
// 64x128 tile, BK=32, 256 threads, 4x8 microtile (32 FMA/thread/kk).
// VGPR target <=128 via __launch_bounds__(256,4): 4 waves/SIMD = 16 waves/CU.
// Prefetch next K-tile's global loads BEFORE computing current (latency hidden
// under ~2048 VALU cycles of FMA).
// Epilogue: el/er partial dot per thread, 8-lane shfl_xor reduce (each 128-col
// block contains exactly 2 complete heads).
#define BM 64
#define BN 128
#define BK 32
#define LDA_S (BM + 4)    // 68
#define LDB_S (BN + 4)    // 132
__global__ __launch_bounds__(256, 4) void k_gemm(const float* __restrict__ A, int lda,
                                                 const float* __restrict__ B,
                                                 float* __restrict__ C, int M,
                                                 const float* __restrict__ al,
                                                 const float* __restrict__ ar,
                                                 float* __restrict__ el,
                                                 float* __restrict__ er) {
    __shared__ float As[BK][LDA_S];
    __shared__ float Bs[BK][LDB_S];
    const int tid = threadIdx.x;
    const int tr = tid >> 4;       // 0..15 -> row group (4 rows)
    const int tc = tid & 15;       // 0..15 -> col group (8 cols)
    const int brow = blockIdx.x * BM;
    const int bcol = blockIdx.y * BN;
    float acc[4][8] = {};

    // A stage: 64 rows x 32 k = 512 float4; 2/thread. row=idx>>3, kq=(idx&7)*4
    // B stage: 32 k x 128 col = 1024 float4; 4/thread. kk=idx>>5, col=(idx&31)*4
    float4 pa[2], pb[4];
    int a_row[2];
#pragma unroll
    for (int i = 0; i < 2; ++i) {
        int idx = tid + i * 256;
        a_row[i] = idx >> 3;
    }

    // prologue: load tile k0=0
#pragma unroll
    for (int i = 0; i < 2; ++i) {
        int idx = tid + i * 256;
        int gr = brow + a_row[i];
        int kq = (idx & 7) * 4;
        pa[i] = (gr < M) ? *(const float4*)&A[(size_t)gr * lda + kq]
                         : make_float4(0.f, 0.f, 0.f, 0.f);
    }
#pragma unroll
    for (int i = 0; i < 4; ++i) {
        int idx = tid + i * 256;
        int kk = idx >> 5;
        int col = (idx & 31) * 4;
        pb[i] = *(const float4*)&B[(size_t)kk * 256 + bcol + col];
    }

    for (int k0 = 0; k0 < 256; k0 += BK) {
        __syncthreads();   // previous compute done; LDS safe to overwrite
#pragma unroll
        for (int i = 0; i < 2; ++i) {
            int idx = tid + i * 256;
            int kq = (idx & 7) * 4;
            As[kq + 0][a_row[i]] = pa[i].x;
            As[kq + 1][a_row[i]] = pa[i].y;
            As[kq + 2][a_row[i]] = pa[i].z;
            As[kq + 3][a_row[i]] = pa[i].w;
        }
#pragma unroll
        for (int i = 0; i < 4; ++i) {
            int idx = tid + i * 256;
            int kk = idx >> 5;
            int col = (idx & 31) * 4;
            *(float4*)&Bs[kk][col] = pb[i];
        }
        __syncthreads();   // LDS ready

        // issue NEXT tile's global loads before compute (latency hidden)
        int kn = k0 + BK;
        if (kn < 256) {
#pragma unroll
            for (int i = 0; i < 2; ++i) {
                int idx = tid + i * 256;
                int gr = brow + a_row[i];
                int kq = (idx & 7) * 4;
                pa[i] = (gr < M) ? *(const float4*)&A[(size_t)gr * lda + kn + kq]
                                 : make_float4(0.f, 0.f, 0.f, 0.f);
            }
#pragma unroll
            for (int i = 0; i < 4; ++i) {
                int idx = tid + i * 256;
                int kk = idx >> 5;
                int col = (idx & 31) * 4;
                pb[i] = *(const float4*)&B[(size_t)(kn + kk) * 256 + bcol + col];
            }
        }

        // compute current tile
#pragma unroll
        for (int kk = 0; kk < BK; ++kk) {
            float4 a = *(const float4*)&As[kk][tr * 4];
            float4 b0 = *(const float4*)&Bs[kk][tc * 8];
            float4 b1 = *(const float4*)&Bs[kk][tc * 8 + 4];
            const float av[4] = {a.x, a.y, a.z, a.w};
            const float bv[8] = {b0.x, b0.y, b0.z, b0.w, b1.x, b1.y, b1.z, b1.w};
#pragma unroll
            for (int i = 0; i < 4; ++i)
#pragma unroll
                for (int j = 0; j < 8; ++j)
                    acc[i][j] += av[i] * bv[j];
        }
    }

    // ---- store C ----
#pragma unroll
    for (int i = 0; i < 4; ++i) {
        int gr = brow + tr * 4 + i;
        if (gr >= M) continue;
        float4 v0 = make_float4(acc[i][0], acc[i][1], acc[i][2], acc[i][3]);
        float4 v1 = make_float4(acc[i][4], acc[i][5], acc[i][6], acc[i][7]);
        *(float4*)&C[(size_t)gr * 256 + bcol + tc * 8] = v0;
        *(float4*)&C[(size_t)gr * 256 + bcol + tc * 8 + 4] = v1;
    }

    // ---- fused el/er epilogue ----
    // this thread's 8 cols (bcol + tc*8 .. +7) lie entirely in head h = (bcol + tc*8)>>6
    float alv[8], arv[8];
    {
        float4 a0 = *(const float4*)&al[bcol + tc * 8];
        float4 a1 = *(const float4*)&al[bcol + tc * 8 + 4];
        float4 r0 = *(const float4*)&ar[bcol + tc * 8];
        float4 r1 = *(const float4*)&ar[bcol + tc * 8 + 4];
        alv[0]=a0.x; alv[1]=a0.y; alv[2]=a0.z; alv[3]=a0.w;
        alv[4]=a1.x; alv[5]=a1.y; alv[6]=a1.z; alv[7]=a1.w;
        arv[0]=r0.x; arv[1]=r0.y; arv[2]=r0.z; arv[3]=r0.w;
        arv[4]=r1.x; arv[5]=r1.y; arv[6]=r1.z; arv[7]=r1.w;
    }
    int h = (bcol >> 6) + (tc >> 3);   // 2 heads per 128-col block
#pragma unroll
    for (int i = 0; i < 4; ++i) {
        float pl = 0.f, pr = 0.f;
#pragma unroll
        for (int j = 0; j < 8; ++j) { pl += acc[i][j] * alv[j]; pr += acc[i][j] * arv[j]; }
        // reduce over the 8 threads (tc&7 groups) sharing this row+head;
        // lanes form groups of 8 consecutive lanes (base multiple of 8)
#pragma unroll
        for (int off = 1; off <= 4; off <<= 1) {
            pl += __shfl_xor(pl, off, 64);
            pr += __shfl_xor(pr, off, 64);
        }
        int gr = brow + tr * 4 + i;
        if ((tc & 7) == 0 && gr < M) {
            el[gr * HEADS + h] = pl;
            er[gr * HEADS + h] = pr;
        }
    }
}

// ---------------- CSR build (once per launch; shared by both layers) ----------------
__global__ void k_zero_counts(int* __restrict__ counts) {
    int i = blockIdx.x * blockDim.x + threadIdx.x;
    if (i < N_NODES) counts[i] = 0;
}
__global__ void k_hist(const int* __restrict__ dst, int* __restrict__ counts) {
    int e = blockIdx.x * blockDim.x + threadIdx.x;
    if (e < N_EDGES) atomicAdd(&counts[dst[e]], 1);
}
__global__ void k_scan1(const int* __restrict__ counts, int* __restrict__ excl,
                        int* __restrict__ blocksums) {
    __shared__ int s[SCAN_B];
    int tid = threadIdx.x;
    int i = blockIdx.x * SCAN_B + tid;
    int v = (i < N_NODES) ? counts[i] : 0;
    s[tid] = v;
    __syncthreads();
    for (int off = 1; off < SCAN_B; off <<= 1) {
        int t = (tid >= off) ? s[tid - off] : 0;
        __syncthreads();
        s[tid] += t;
        __syncthreads();
    }
    if (i < N_NODES) excl[i] = s[tid] - v;
    if (tid == SCAN_B - 1) blocksums[blockIdx.x] = s[tid];
}
__global__ void k_scan2(int* __restrict__ blocksums) {   // single block; NBLK <= 256
    __shared__ int s[SCAN_B];
    int tid = threadIdx.x;
    int v = (tid < NBLK) ? blocksums[tid] : 0;
    s[tid] = v;
    __syncthreads();
    for (int off = 1; off < SCAN_B; off <<= 1) {
        int t = (tid >= off) ? s[tid - off] : 0;
        __syncthreads();
        s[tid] += t;
        __syncthreads();
    }
    if (tid < NBLK) blocksums[tid] = s[tid] - v;   // exclusive
}
__global__ void k_scan3(const int* __restrict__ excl, const int* __restrict__ blocksums,
                        int* __restrict__ row_start, int* __restrict__ cursor) {
    int i = blockIdx.x * blockDim.x + threadIdx.x;
    if (i >= N_NODES) return;
    int r = excl[i] + blocksums[i >> 8];
    row_start[i] = r;
    cursor[i] = r;
}
__global__ void k_place(const int* __restrict__ src, const int* __restrict__ dst,
                        int* __restrict__ cursor, int* __restrict__ csr_src) {
    int e = blockIdx.x * blockDim.x + threadIdx.x;
    if (e >= N_EDGES) return;
    int pos = atomicAdd(&cursor[dst[e]], 1);
    csr_src[pos] = src[e];
}

// ---------------- fused edge softmax + aggregate: one wave per dst node ----------------
// Single pass, online softmax: running max m, denom, acc; branch-free rescale.
__global__ void k_gather(const int* __restrict__ row_start, const int* __restrict__ counts,
                         const int* __restrict__ csr_src,
                         const float* __restrict__ feat,
                         const float* __restrict__ el, const float* __restrict__ er,
                         const float* __restrict__ bias,
                         float* __restrict__ out_slice, int apply_elu) {
    int gtid = blockIdx.x * blockDim.x + threadIdx.x;
    int node = gtid >> 6;
    if (node >= N_NODES) return;
    int lane = threadIdx.x & 63;
    int h = lane >> 4;                           // head of this lane's 4 channels
    float4 bv = *(const float4*)&bias[lane * 4];
    int start = row_start[node];
    int cnt = counts[node];
    float4 acc = make_float4(0.f, 0.f, 0.f, 0.f);
    if (cnt > 0) {
        float erd = er[node * HEADS + h];
        float m = -1e30f, denom = 0.f;
        for (int i = 0; i < cnt; ++i) {
            int s = csr_src[start + i];
            float v = lrelu(el[s * HEADS + h] + erd);
            float mn = fmaxf(m, v);
            float scale = __expf(m - mn);        // 1 when no new max
            float ex = __expf(v - mn);
            m = mn;
            denom = denom * scale + ex;
            float4 f = *(const float4*)&feat[(size_t)s * FDIM + lane * 4];
            acc.x = acc.x * scale + ex * f.x;
            acc.y = acc.y * scale + ex * f.y;
            acc.z = acc.z * scale + ex * f.z;
            acc.w = acc.w * scale + ex * f.w;
        }
        float inv = 1.f / denom;
        acc.x = acc.x * inv + bv.x; acc.y = acc.y * inv + bv.y;
        acc.z = acc.z * inv + bv.z; acc.w = acc.w * inv + bv.w;
    } else {
        acc = bv;   // empty segment: message sum is 0, out = bias
    }
    if (apply_elu) {
        acc.x = acc.x > 0.f ? acc.x : expm1f(acc.x);
        acc.y = acc.y > 0.f ? acc.y : expm1f(acc.y);
        acc.z = acc.z > 0.f ? acc.z : expm1f(acc.z);
        acc.w = acc.w > 0.f ? acc.w : expm1f(acc.w);
    }
    *(float4*)&out_slice[(size_t)node * OUT_STRIDE + lane * 4] = acc;
}

// ---------------- per-layer driver ----------------
static void run_layer(const float* in, int lda,
                      const float* W, const float* al, const float* ar, const float* bias,
                      float* out_slice, int apply_elu,
                      const int* row_start, const int* counts, const int* csr_src,
                      float* feat, float* el, float* er, hipStream_t stream) {
    dim3 ggrid((N_NODES + BM - 1) / BM, 256 / BN);
    k_gemm<<<ggrid, 256, 0, stream>>>(in, lda, W, feat, N_NODES, al, ar, el, er);
    k_gather<<<(N_NODES * 64 + 255) / 256, 256, 0, stream>>>(
        row_start, counts, csr_src, feat, el, er, bias, out_slice, apply_elu);
}

extern "C" void kernel_launch(void* const* d_in, const int* in_sizes, int n_in,
                              void* d_out, int out_size, void* d_ws, size_t ws_size,
                              hipStream_t stream) {
    const float* x   = (const float*)d_in[0];
    const int*   src = (const int*)d_in[1];
    const int*   dst = (const int*)d_in[2];
    const float* W1  = (const float*)d_in[3];
    const float* al1 = (const float*)d_in[4];
    const float* ar1 = (const float*)d_in[5];
    const float* b1  = (const float*)d_in[6];
    const float* W2  = (const float*)d_in[7];
    const float* al2 = (const float*)d_in[8];
    const float* ar2 = (const float*)d_in[9];
    const float* b2  = (const float*)d_in[10];
    float* out = (float*)d_out;

    // workspace carve-up; guard against undersized ws (fail validation, not the GPU)
    size_t need_bytes = ((size_t)N_NODES * FDIM + 2u * N_NODES * HEADS) * 4u  // feat, el, er
                      + ((size_t)4 * N_NODES + 256 + N_EDGES) * 4u;           // csr ints
    if (ws_size < need_bytes) return;

    float* ws        = (float*)d_ws;
    float* feat      = ws;                                    // N*256 floats
    float* el        = feat + (size_t)N_NODES * FDIM;         // N*4
    float* er        = el + N_NODES * HEADS;                  // N*4
    int*   counts    = (int*)(er + N_NODES * HEADS);          // N
    int*   excl      = counts + N_NODES;                      // N
    int*   row_start = excl + N_NODES;                        // N
    int*   cursor    = row_start + N_NODES;                   // N
    int*   blocksums = cursor + N_NODES;                      // 256
    int*   csr_src   = blocksums + 256;                       // E

    // ---- CSR build (shared by both layers) ----
    k_zero_counts<<<(N_NODES + 255) / 256, 256, 0, stream>>>(counts);
    k_hist<<<(N_EDGES + 255) / 256, 256, 0, stream>>>(dst, counts);
    k_scan1<<<NBLK, SCAN_B, 0, stream>>>(counts, excl, blocksums);
    k_scan2<<<1, SCAN_B, 0, stream>>>(blocksums);
    k_scan3<<<(N_NODES + 255) / 256, 256, 0, stream>>>(excl, blocksums, row_start, cursor);
    k_place<<<(N_EDGES + 255) / 256, 256, 0, stream>>>(src, dst, cursor, csr_src);

    // ---- x -> out[:, 0:256] ----
    k_copy_x<<<(N_NODES * 64 + 255) / 256, 256, 0, stream>>>(x, out);

    // ---- layer 1: x -> out[:, 256:512] (ELU) ----
    run_layer(x, FDIM, W1, al1, ar1, b1, out + 256, 1,
              row_start, counts, csr_src, feat, el, er, stream);

    // ---- layer 2: h1 (strided in out) -> out[:, 512:768] ----
    run_layer(out + 256, OUT_STRIDE, W2, al2, ar2, b2, out + 512, 0,
              row_start, counts, csr_src, feat, el, er, stream);
}

// Round 5
// 801.483 us; speedup vs baseline: 1.0776x; 1.0535x over previous
//
#include <hip/hip_runtime.h>
#include <hip/hip_bf16.h>

#define N_NODES 50000
#define N_EDGES 800000
#define HEADS 4
#define FDIM 256      // HEADS * 64
#define OUT_STRIDE 768
#define SCAN_B 256
#define NBLK ((N_NODES + SCAN_B - 1) / SCAN_B)   // 196 (<= 256, fits single scan block)

// ---------------- helpers ----------------
__device__ __forceinline__ float lrelu(float v) { return v > 0.f ? v : 0.2f * v; }

// ---------------- copy x into d_out[:, 0:256] ----------------
__global__ void k_copy_x(const float* __restrict__ x, float* __restrict__ out) {
    int idx = blockIdx.x * blockDim.x + threadIdx.x;   // N*64 threads (float4 each)
    if (idx >= N_NODES * 64) return;
    int n = idx >> 6, q = idx & 63;
    float4 v = *(const float4*)&x[(size_t)n * FDIM + q * 4];
    *(float4*)&out[(size_t)n * OUT_STRIDE + q * 4] = v;
}

// ---------------- fp32 GEMM + fused el/er epilogue ----------------
// C[M x 256] = A[M x 256 (lda)] @ B[256 x 256]
// 64x128 tile, BK=32, 256 threads, 4x8 microtile.
// Thread (tr=tid>>4, tc=tid&15) owns rows tr*4..+3, cols {tc*4..+3, 64+tc*4..+3}.
// A stored transposed in LDS with XOR swizzle: A[row][k] -> As[k][row ^ (((k>>2)&3)<<3)]
//   store: 64 lanes -> 32 banks x2 (2-way, free);  read: b128 contiguous, conflict-free.
// B read at tc*4 / tc*4+64: 16 addrs over 256B contiguous (2-way, free).
// launch_bounds(256,2): VGPR cap >=128 -> NO SPILL (round-4's (256,4) forced 64 VGPR
//   and spilled ~380MB/dispatch of scratch traffic).
#define BM 64
#define BN 128
#define BK 32
#define LDA_S (BM + 4)    // 68 floats: rows 16B-aligned, row-start banks staggered by 4
#define LDB_S (BN + 4)    // 132
__global__ __launch_bounds__(256, 2) void k_gemm(const float* __restrict__ A, int lda,
                                                 const float* __restrict__ B,
                                                 float* __restrict__ C, int M,
                                                 const float* __restrict__ al,
                                                 const float* __restrict__ ar,
                                                 float* __restrict__ el,
                                                 float* __restrict__ er) {
    __shared__ float As[BK][LDA_S];
    __shared__ float Bs[BK][LDB_S];
    const int tid = threadIdx.x;
    const int tr = tid >> 4;       // 0..15 -> row group (4 rows)
    const int tc4 = (tid & 15) * 4;
    const int rowbase = tr * 4;
    const int brow = blockIdx.x * BM;
    const int bcol = blockIdx.y * BN;
    float acc[4][8] = {};

    // A stage: 64 rows x 32 k = 512 float4; 2/thread. row=idx>>3, kq=(idx&7)*4
    // B stage: 32 k x 128 col = 1024 float4; 4/thread. kk=idx>>5, col=(idx&31)*4
    float4 pa[2], pb[4];

    // prologue: load tile k0=0
#pragma unroll
    for (int i = 0; i < 2; ++i) {
        int idx = tid + i * 256;
        int gr = brow + (idx >> 3);
        int kq = (idx & 7) * 4;
        pa[i] = (gr < M) ? *(const float4*)&A[(size_t)gr * lda + kq]
                         : make_float4(0.f, 0.f, 0.f, 0.f);
    }
#pragma unroll
    for (int i = 0; i < 4; ++i) {
        int idx = tid + i * 256;
        int kk = idx >> 5;
        int col = (idx & 31) * 4;
        pb[i] = *(const float4*)&B[(size_t)kk * 256 + bcol + col];
    }

    for (int k0 = 0; k0 < 256; k0 += BK) {
        __syncthreads();   // previous compute done; LDS safe to overwrite
#pragma unroll
        for (int i = 0; i < 2; ++i) {
            int idx = tid + i * 256;
            int row = idx >> 3;
            int kq = (idx & 7) * 4;
            int col = row ^ ((idx & 3) << 3);   // swizzle: (kq/4)&3 == idx&3 for all 4 comps
            As[kq + 0][col] = pa[i].x;
            As[kq + 1][col] = pa[i].y;
            As[kq + 2][col] = pa[i].z;
            As[kq + 3][col] = pa[i].w;
        }
#pragma unroll
        for (int i = 0; i < 4; ++i) {
            int idx = tid + i * 256;
            int kk = idx >> 5;
            int col = (idx & 31) * 4;
            *(float4*)&Bs[kk][col] = pb[i];
        }
        __syncthreads();   // LDS ready

        // issue NEXT tile's global loads before compute (latency hidden under FMAs)
        int kn = k0 + BK;
        if (kn < 256) {
#pragma unroll
            for (int i = 0; i < 2; ++i) {
                int idx = tid + i * 256;
                int gr = brow + (idx >> 3);
                int kq = (idx & 7) * 4;
                pa[i] = (gr < M) ? *(const float4*)&A[(size_t)gr * lda + kn + kq]
                                 : make_float4(0.f, 0.f, 0.f, 0.f);
            }
#pragma unroll
            for (int i = 0; i < 4; ++i) {
                int idx = tid + i * 256;
                int kk = idx >> 5;
                int col = (idx & 31) * 4;
                pb[i] = *(const float4*)&B[(size_t)(kn + kk) * 256 + bcol + col];
            }
        }

        // compute current tile
#pragma unroll
        for (int kk = 0; kk < BK; ++kk) {
            const int sw = ((kk >> 2) & 3) << 3;
            float4 a  = *(const float4*)&As[kk][rowbase ^ sw];
            float4 b0 = *(const float4*)&Bs[kk][tc4];
            float4 b1 = *(const float4*)&Bs[kk][tc4 + 64];
            const float av[4] = {a.x, a.y, a.z, a.w};
            const float bv[8] = {b0.x, b0.y, b0.z, b0.w, b1.x, b1.y, b1.z, b1.w};
#pragma unroll
            for (int i = 0; i < 4; ++i)
#pragma unroll
                for (int j = 0; j < 8; ++j)
                    acc[i][j] += av[i] * bv[j];
        }
    }

    // ---- store C ----
#pragma unroll
    for (int i = 0; i < 4; ++i) {
        int gr = brow + rowbase + i;
        if (gr >= M) continue;
        float4 v0 = make_float4(acc[i][0], acc[i][1], acc[i][2], acc[i][3]);
        float4 v1 = make_float4(acc[i][4], acc[i][5], acc[i][6], acc[i][7]);
        *(float4*)&C[(size_t)gr * 256 + bcol + tc4] = v0;
        *(float4*)&C[(size_t)gr * 256 + bcol + 64 + tc4] = v1;
    }

    // ---- fused el/er epilogue ----
    // cols {bcol+tc4..+3} lie in head hA = bcol>>6; cols {bcol+64+tc4..+3} in hA+1
    float4 alA = *(const float4*)&al[bcol + tc4];
    float4 alB = *(const float4*)&al[bcol + 64 + tc4];
    float4 arA = *(const float4*)&ar[bcol + tc4];
    float4 arB = *(const float4*)&ar[bcol + 64 + tc4];
    int hA = bcol >> 6;
#pragma unroll
    for (int i = 0; i < 4; ++i) {
        float plA = acc[i][0]*alA.x + acc[i][1]*alA.y + acc[i][2]*alA.z + acc[i][3]*alA.w;
        float prA = acc[i][0]*arA.x + acc[i][1]*arA.y + acc[i][2]*arA.z + acc[i][3]*arA.w;
        float plB = acc[i][4]*alB.x + acc[i][5]*alB.y + acc[i][6]*alB.z + acc[i][7]*alB.w;
        float prB = acc[i][4]*arB.x + acc[i][5]*arB.y + acc[i][6]*arB.z + acc[i][7]*arB.w;
        // reduce over the 16 threads (tc groups) sharing this row; 16-lane groups
#pragma unroll
        for (int off = 1; off <= 8; off <<= 1) {
            plA += __shfl_xor(plA, off, 64);
            prA += __shfl_xor(prA, off, 64);
            plB += __shfl_xor(plB, off, 64);
            prB += __shfl_xor(prB, off, 64);
        }
        int gr = brow + rowbase + i;
        if ((tid & 15) == 0 && gr < M) {
            el[gr * HEADS + hA] = plA;
            er[gr * HEADS + hA] = prA;
            el[gr * HEADS + hA + 1] = plB;
            er[gr * HEADS + hA + 1] = prB;
        }
    }
}

// ---------------- CSR build (once per launch; shared by both layers) ----------------
__global__ void k_zero_counts(int* __restrict__ counts) {
    int i = blockIdx.x * blockDim.x + threadIdx.x;
    if (i < N_NODES) counts[i] = 0;
}
__global__ void k_hist(const int* __restrict__ dst, int* __restrict__ counts) {
    int e = blockIdx.x * blockDim.x + threadIdx.x;
    if (e < N_EDGES) atomicAdd(&counts[dst[e]], 1);
}
__global__ void k_scan1(const int* __restrict__ counts, int* __restrict__ excl,
                        int* __restrict__ blocksums) {
    __shared__ int s[SCAN_B];
    int tid = threadIdx.x;
    int i = blockIdx.x * SCAN_B + tid;
    int v = (i < N_NODES) ? counts[i] : 0;
    s[tid] = v;
    __syncthreads();
    for (int off = 1; off < SCAN_B; off <<= 1) {
        int t = (tid >= off) ? s[tid - off] : 0;
        __syncthreads();
        s[tid] += t;
        __syncthreads();
    }
    if (i < N_NODES) excl[i] = s[tid] - v;
    if (tid == SCAN_B - 1) blocksums[blockIdx.x] = s[tid];
}
__global__ void k_scan2(int* __restrict__ blocksums) {   // single block; NBLK <= 256
    __shared__ int s[SCAN_B];
    int tid = threadIdx.x;
    int v = (tid < NBLK) ? blocksums[tid] : 0;
    s[tid] = v;
    __syncthreads();
    for (int off = 1; off < SCAN_B; off <<= 1) {
        int t = (tid >= off) ? s[tid - off] : 0;
        __syncthreads();
        s[tid] += t;
        __syncthreads();
    }
    if (tid < NBLK) blocksums[tid] = s[tid] - v;   // exclusive
}
__global__ void k_scan3(const int* __restrict__ excl, const int* __restrict__ blocksums,
                        int* __restrict__ row_start, int* __restrict__ cursor) {
    int i = blockIdx.x * blockDim.x + threadIdx.x;
    if (i >= N_NODES) return;
    int r = excl[i] + blocksums[i >> 8];
    row_start[i] = r;
    cursor[i] = r;
}
__global__ void k_place(const int* __restrict__ src, const int* __restrict__ dst,
                        int* __restrict__ cursor, int* __restrict__ csr_src) {
    int e = blockIdx.x * blockDim.x + threadIdx.x;
    if (e >= N_EDGES) return;
    int pos = atomicAdd(&cursor[dst[e]], 1);
    csr_src[pos] = src[e];
}

// ---------------- fused edge softmax + aggregate: one wave per dst node ----------------
// Single pass, online softmax: running max m, denom, acc; branch-free rescale.
__global__ void k_gather(const int* __restrict__ row_start, const int* __restrict__ counts,
                         const int* __restrict__ csr_src,
                         const float* __restrict__ feat,
                         const float* __restrict__ el, const float* __restrict__ er,
                         const float* __restrict__ bias,
                         float* __restrict__ out_slice, int apply_elu) {
    int gtid = blockIdx.x * blockDim.x + threadIdx.x;
    int node = gtid >> 6;
    if (node >= N_NODES) return;
    int lane = threadIdx.x & 63;
    int h = lane >> 4;                           // head of this lane's 4 channels
    float4 bv = *(const float4*)&bias[lane * 4];
    int start = row_start[node];
    int cnt = counts[node];
    float4 acc = make_float4(0.f, 0.f, 0.f, 0.f);
    if (cnt > 0) {
        float erd = er[node * HEADS + h];
        float m = -1e30f, denom = 0.f;
        for (int i = 0; i < cnt; ++i) {
            int s = csr_src[start + i];
            float v = lrelu(el[s * HEADS + h] + erd);
            float mn = fmaxf(m, v);
            float scale = __expf(m - mn);        // 1 when no new max
            float ex = __expf(v - mn);
            m = mn;
            denom = denom * scale + ex;
            float4 f = *(const float4*)&feat[(size_t)s * FDIM + lane * 4];
            acc.x = acc.x * scale + ex * f.x;
            acc.y = acc.y * scale + ex * f.y;
            acc.z = acc.z * scale + ex * f.z;
            acc.w = acc.w * scale + ex * f.w;
        }
        float inv = 1.f / denom;
        acc.x = acc.x * inv + bv.x; acc.y = acc.y * inv + bv.y;
        acc.z = acc.z * inv + bv.z; acc.w = acc.w * inv + bv.w;
    } else {
        acc = bv;   // empty segment: message sum is 0, out = bias
    }
    if (apply_elu) {
        acc.x = acc.x > 0.f ? acc.x : expm1f(acc.x);
        acc.y = acc.y > 0.f ? acc.y : expm1f(acc.y);
        acc.z = acc.z > 0.f ? acc.z : expm1f(acc.z);
        acc.w = acc.w > 0.f ? acc.w : expm1f(acc.w);
    }
    *(float4*)&out_slice[(size_t)node * OUT_STRIDE + lane * 4] = acc;
}

// ---------------- per-layer driver ----------------
static void run_layer(const float* in, int lda,
                      const float* W, const float* al, const float* ar, const float* bias,
                      float* out_slice, int apply_elu,
                      const int* row_start, const int* counts, const int* csr_src,
                      float* feat, float* el, float* er, hipStream_t stream) {
    dim3 ggrid((N_NODES + BM - 1) / BM, 256 / BN);
    k_gemm<<<ggrid, 256, 0, stream>>>(in, lda, W, feat, N_NODES, al, ar, el, er);
    k_gather<<<(N_NODES * 64 + 255) / 256, 256, 0, stream>>>(
        row_start, counts, csr_src, feat, el, er, bias, out_slice, apply_elu);
}

extern "C" void kernel_launch(void* const* d_in, const int* in_sizes, int n_in,
                              void* d_out, int out_size, void* d_ws, size_t ws_size,
                              hipStream_t stream) {
    const float* x   = (const float*)d_in[0];
    const int*   src = (const int*)d_in[1];
    const int*   dst = (const int*)d_in[2];
    const float* W1  = (const float*)d_in[3];
    const float* al1 = (const float*)d_in[4];
    const float* ar1 = (const float*)d_in[5];
    const float* b1  = (const float*)d_in[6];
    const float* W2  = (const float*)d_in[7];
    const float* al2 = (const float*)d_in[8];
    const float* ar2 = (const float*)d_in[9];
    const float* b2  = (const float*)d_in[10];
    float* out = (float*)d_out;

    // workspace carve-up; guard against undersized ws (fail validation, not the GPU)
    size_t need_bytes = ((size_t)N_NODES * FDIM + 2u * N_NODES * HEADS) * 4u  // feat, el, er
                      + ((size_t)4 * N_NODES + 256 + N_EDGES) * 4u;           // csr ints
    if (ws_size < need_bytes) return;

    float* ws        = (float*)d_ws;
    float* feat      = ws;                                    // N*256 floats
    float* el        = feat + (size_t)N_NODES * FDIM;         // N*4
    float* er        = el + N_NODES * HEADS;                  // N*4
    int*   counts    = (int*)(er + N_NODES * HEADS);          // N
    int*   excl      = counts + N_NODES;                      // N
    int*   row_start = excl + N_NODES;                        // N
    int*   cursor    = row_start + N_NODES;                   // N
    int*   blocksums = cursor + N_NODES;                      // 256
    int*   csr_src   = blocksums + 256;                       // E

    // ---- CSR build (shared by both layers) ----
    k_zero_counts<<<(N_NODES + 255) / 256, 256, 0, stream>>>(counts);
    k_hist<<<(N_EDGES + 255) / 256, 256, 0, stream>>>(dst, counts);
    k_scan1<<<NBLK, SCAN_B, 0, stream>>>(counts, excl, blocksums);
    k_scan2<<<1, SCAN_B, 0, stream>>>(blocksums);
    k_scan3<<<(N_NODES + 255) / 256, 256, 0, stream>>>(excl, blocksums, row_start, cursor);
    k_place<<<(N_EDGES + 255) / 256, 256, 0, stream>>>(src, dst, cursor, csr_src);

    // ---- x -> out[:, 0:256] ----
    k_copy_x<<<(N_NODES * 64 + 255) / 256, 256, 0, stream>>>(x, out);

    // ---- layer 1: x -> out[:, 256:512] (ELU) ----
    run_layer(x, FDIM, W1, al1, ar1, b1, out + 256, 1,
              row_start, counts, csr_src, feat, el, er, stream);

    // ---- layer 2: h1 (strided in out) -> out[:, 512:768] ----
    run_layer(out + 256, OUT_STRIDE, W2, al2, ar2, b2, out + 512, 0,
              row_start, counts, csr_src, feat, el, er, stream);
}

// Round 6
// 712.013 us; speedup vs baseline: 1.2130x; 1.1257x over previous
//
#include <hip/hip_runtime.h>
#include <hip/hip_bf16.h>

#define N_NODES 50000
#define N_EDGES 800000
#define HEADS 4
#define FDIM 256      // HEADS * 64
#define OUT_STRIDE 768
#define SCAN_B 256
#define NBLK ((N_NODES + SCAN_B - 1) / SCAN_B)   // 196 (<= 256, fits single scan block)

typedef __attribute__((ext_vector_type(8))) short short8;   // 8 bf16 = 4 VGPR
typedef __attribute__((ext_vector_type(4))) float f32x4;    // mfma C/D frag

// ---------------- helpers ----------------
__device__ __forceinline__ float lrelu(float v) { return v > 0.f ? v : 0.2f * v; }

__device__ __forceinline__ unsigned short f2bf(float f) {   // RNE fp32 -> bf16 bits
    unsigned u = __float_as_uint(f);
    return (unsigned short)((u + 0x7fffu + ((u >> 16) & 1u)) >> 16);
}
__device__ __forceinline__ float bf2f(unsigned short s) {
    return __uint_as_float(((unsigned)s) << 16);
}

// ---------------- copy x into d_out[:, 0:256] ----------------
__global__ void k_copy_x(const float* __restrict__ x, float* __restrict__ out) {
    int idx = blockIdx.x * blockDim.x + threadIdx.x;   // N*64 threads (float4 each)
    if (idx >= N_NODES * 64) return;
    int n = idx >> 6, q = idx & 63;
    float4 v = *(const float4*)&x[(size_t)n * FDIM + q * 4];
    *(float4*)&out[(size_t)n * OUT_STRIDE + q * 4] = v;
}

// ---------------- W -> B^T split-bf16 (hi/lo), once per layer ----------------
// bt[col*256 + k] = split(W[k*256 + col]); b-frag reads are then 16B contiguous.
__global__ void k_convW(const float* __restrict__ W,
                        unsigned short* __restrict__ bt_hi,
                        unsigned short* __restrict__ bt_lo) {
    int t = blockIdx.x * blockDim.x + threadIdx.x;   // 65536
    int k = t >> 8, col = t & 255;                   // read coalesced over col
    float f = W[k * 256 + col];
    unsigned short h = f2bf(f);
    bt_hi[(size_t)col * 256 + k] = h;
    bt_lo[(size_t)col * 256 + k] = f2bf(f - bf2f(h));
}

// ---------------- split-bf16 MFMA GEMM + fused el/er epilogue ----------------
// C[M x 256] = A[M x 256 (lda)] @ B[256 x 256], fp32-accurate via 3-product split:
//   a*b ~= ahi*bhi + alo*bhi + ahi*blo   (lo*lo ~2^-16 rel, dropped)
// Block: 512 thr = 8 waves; block tile 64 rows x 256 cols (full N -> A read once).
// Wave w: rows (w>>2)*32 (2 frags of 16), cols (w&3)*64 (4 frags of 16) = 1 head.
// A: whole K staged in LDS as hi/lo bf16, XOR-swizzled 16B chunks (store/read use
//    the same a_idx() -> correct regardless of bank math). ONE barrier total.
// B: read as B^T hi/lo bf16 direct from global (256KB, L2-resident). No LDS.
// mfma_f32_16x16x32_bf16 layouts (verified, learn_hip m89/m91/m97):
//   A-frag: row=lane&15, k=8*(lane>>4)+i ; B-frag: col=lane&15 (B^T row), same k
//   C/D:    col=lane&15, row=(lane>>4)*4+reg
__device__ __forceinline__ int a_idx(int row, int cq) {      // ushort index in As
    return row * 256 + ((cq ^ (row & 31)) << 3);             // 16B-chunk XOR swizzle
}

__global__ __launch_bounds__(512) void k_gemm_mfma(
        const float* __restrict__ A, int lda,
        const unsigned short* __restrict__ bt_hi, const unsigned short* __restrict__ bt_lo,
        float* __restrict__ C, int M,
        const float* __restrict__ al, const float* __restrict__ ar,
        float* __restrict__ el, float* __restrict__ er) {
    __shared__ __align__(16) unsigned short As_hi[64 * 256];   // 32 KB
    __shared__ __align__(16) unsigned short As_lo[64 * 256];   // 32 KB
    const int tid = threadIdx.x;
    const int brow = blockIdx.x * 64;

    // ---- stage A rows [brow..brow+63] x K=256 as split bf16 ----
    {
        const int row = tid >> 3;          // 0..63
        const int seg = tid & 7;           // 0..7 -> cols seg*32..+31
        const int grow = brow + row;
        const bool valid = grow < M;
        const float* ap = A + (size_t)grow * lda + seg * 32;
#pragma unroll
        for (int c = 0; c < 4; ++c) {
            float fv[8];
            if (valid) {
                float4 f0 = *(const float4*)(ap + c * 8);
                float4 f1 = *(const float4*)(ap + c * 8 + 4);
                fv[0]=f0.x; fv[1]=f0.y; fv[2]=f0.z; fv[3]=f0.w;
                fv[4]=f1.x; fv[5]=f1.y; fv[6]=f1.z; fv[7]=f1.w;
            } else {
#pragma unroll
                for (int j = 0; j < 8; ++j) fv[j] = 0.f;
            }
            short8 vh, vl;
#pragma unroll
            for (int j = 0; j < 8; ++j) {
                unsigned short h = f2bf(fv[j]);
                vh[j] = (short)h;
                vl[j] = (short)f2bf(fv[j] - bf2f(h));
            }
            int idx = a_idx(row, seg * 4 + c);
            *(short8*)&As_hi[idx] = vh;
            *(short8*)&As_lo[idx] = vl;
        }
    }
    __syncthreads();

    // ---- K loop: 8 steps of K=32, no barriers ----
    const int lane = tid & 63;
    const int w = tid >> 6;
    const int wr = w >> 2;            // 0..1 -> rows wr*32
    const int wc = w & 3;             // 0..3 -> cols wc*64 (= head wc)
    const int ln15 = lane & 15;
    const int kg = lane >> 4;         // 0..3
    f32x4 acc[2][4] = {};

#pragma unroll 2
    for (int ks = 0; ks < 8; ++ks) {
        short8 ah[2], am[2];
#pragma unroll
        for (int rf = 0; rf < 2; ++rf) {
            int idx = a_idx(wr * 32 + rf * 16 + ln15, ks * 4 + kg);
            ah[rf] = *(const short8*)&As_hi[idx];
            am[rf] = *(const short8*)&As_lo[idx];
        }
#pragma unroll
        for (int cf = 0; cf < 4; ++cf) {
            size_t boff = (size_t)(wc * 64 + cf * 16 + ln15) * 256 + ks * 32 + kg * 8;
            short8 bh = *(const short8*)&bt_hi[boff];
            short8 bl = *(const short8*)&bt_lo[boff];
#pragma unroll
            for (int rf = 0; rf < 2; ++rf) {
                acc[rf][cf] = __builtin_amdgcn_mfma_f32_16x16x32_bf16(ah[rf], bh, acc[rf][cf], 0, 0, 0);
                acc[rf][cf] = __builtin_amdgcn_mfma_f32_16x16x32_bf16(am[rf], bh, acc[rf][cf], 0, 0, 0);
                acc[rf][cf] = __builtin_amdgcn_mfma_f32_16x16x32_bf16(ah[rf], bl, acc[rf][cf], 0, 0, 0);
            }
        }
    }

    // ---- epilogue: store C + fused el/er ----
#pragma unroll
    for (int rf = 0; rf < 2; ++rf) {
        float pel[4] = {0.f, 0.f, 0.f, 0.f};
        float per[4] = {0.f, 0.f, 0.f, 0.f};
#pragma unroll
        for (int cf = 0; cf < 4; ++cf) {
            int gcol = wc * 64 + cf * 16 + ln15;
            float alv = al[gcol], arv = ar[gcol];
#pragma unroll
            for (int reg = 0; reg < 4; ++reg) {
                float v = acc[rf][cf][reg];
                int gr = brow + wr * 32 + rf * 16 + kg * 4 + reg;
                if (gr < M) C[(size_t)gr * 256 + gcol] = v;
                pel[reg] += v * alv;
                per[reg] += v * arv;
            }
        }
        // reduce across the 16 lanes (cols) sharing each row
#pragma unroll
        for (int reg = 0; reg < 4; ++reg) {
#pragma unroll
            for (int off = 1; off <= 8; off <<= 1) {
                pel[reg] += __shfl_xor(pel[reg], off, 64);
                per[reg] += __shfl_xor(per[reg], off, 64);
            }
        }
        if (ln15 == 0) {
#pragma unroll
            for (int reg = 0; reg < 4; ++reg) {
                int gr = brow + wr * 32 + rf * 16 + kg * 4 + reg;
                if (gr < M) {
                    el[gr * HEADS + wc] = pel[reg];
                    er[gr * HEADS + wc] = per[reg];
                }
            }
        }
    }
}

// ---------------- CSR build (once per launch; shared by both layers) ----------------
__global__ void k_zero_counts(int* __restrict__ counts) {
    int i = blockIdx.x * blockDim.x + threadIdx.x;
    if (i < N_NODES) counts[i] = 0;
}
__global__ void k_hist(const int* __restrict__ dst, int* __restrict__ counts) {
    int e = blockIdx.x * blockDim.x + threadIdx.x;
    if (e < N_EDGES) atomicAdd(&counts[dst[e]], 1);
}
__global__ void k_scan1(const int* __restrict__ counts, int* __restrict__ excl,
                        int* __restrict__ blocksums) {
    __shared__ int s[SCAN_B];
    int tid = threadIdx.x;
    int i = blockIdx.x * SCAN_B + tid;
    int v = (i < N_NODES) ? counts[i] : 0;
    s[tid] = v;
    __syncthreads();
    for (int off = 1; off < SCAN_B; off <<= 1) {
        int t = (tid >= off) ? s[tid - off] : 0;
        __syncthreads();
        s[tid] += t;
        __syncthreads();
    }
    if (i < N_NODES) excl[i] = s[tid] - v;
    if (tid == SCAN_B - 1) blocksums[blockIdx.x] = s[tid];
}
__global__ void k_scan2(int* __restrict__ blocksums) {   // single block; NBLK <= 256
    __shared__ int s[SCAN_B];
    int tid = threadIdx.x;
    int v = (tid < NBLK) ? blocksums[tid] : 0;
    s[tid] = v;
    __syncthreads();
    for (int off = 1; off < SCAN_B; off <<= 1) {
        int t = (tid >= off) ? s[tid - off] : 0;
        __syncthreads();
        s[tid] += t;
        __syncthreads();
    }
    if (tid < NBLK) blocksums[tid] = s[tid] - v;   // exclusive
}
__global__ void k_scan3(const int* __restrict__ excl, const int* __restrict__ blocksums,
                        int* __restrict__ row_start, int* __restrict__ cursor) {
    int i = blockIdx.x * blockDim.x + threadIdx.x;
    if (i >= N_NODES) return;
    int r = excl[i] + blocksums[i >> 8];
    row_start[i] = r;
    cursor[i] = r;
}
__global__ void k_place(const int* __restrict__ src, const int* __restrict__ dst,
                        int* __restrict__ cursor, int* __restrict__ csr_src) {
    int e = blockIdx.x * blockDim.x + threadIdx.x;
    if (e >= N_EDGES) return;
    int pos = atomicAdd(&cursor[dst[e]], 1);
    csr_src[pos] = src[e];
}

// ---------------- fused edge softmax + aggregate: one wave per dst node ----------------
// Single pass, online softmax: running max m, denom, acc; branch-free rescale.
__global__ void k_gather(const int* __restrict__ row_start, const int* __restrict__ counts,
                         const int* __restrict__ csr_src,
                         const float* __restrict__ feat,
                         const float* __restrict__ el, const float* __restrict__ er,
                         const float* __restrict__ bias,
                         float* __restrict__ out_slice, int apply_elu) {
    int gtid = blockIdx.x * blockDim.x + threadIdx.x;
    int node = gtid >> 6;
    if (node >= N_NODES) return;
    int lane = threadIdx.x & 63;
    int h = lane >> 4;                           // head of this lane's 4 channels
    float4 bv = *(const float4*)&bias[lane * 4];
    int start = row_start[node];
    int cnt = counts[node];
    float4 acc = make_float4(0.f, 0.f, 0.f, 0.f);
    if (cnt > 0) {
        float erd = er[node * HEADS + h];
        float m = -1e30f, denom = 0.f;
        for (int i = 0; i < cnt; ++i) {
            int s = csr_src[start + i];
            float v = lrelu(el[s * HEADS + h] + erd);
            float mn = fmaxf(m, v);
            float scale = __expf(m - mn);        // 1 when no new max
            float ex = __expf(v - mn);
            m = mn;
            denom = denom * scale + ex;
            float4 f = *(const float4*)&feat[(size_t)s * FDIM + lane * 4];
            acc.x = acc.x * scale + ex * f.x;
            acc.y = acc.y * scale + ex * f.y;
            acc.z = acc.z * scale + ex * f.z;
            acc.w = acc.w * scale + ex * f.w;
        }
        float inv = 1.f / denom;
        acc.x = acc.x * inv + bv.x; acc.y = acc.y * inv + bv.y;
        acc.z = acc.z * inv + bv.z; acc.w = acc.w * inv + bv.w;
    } else {
        acc = bv;   // empty segment: message sum is 0, out = bias
    }
    if (apply_elu) {
        acc.x = acc.x > 0.f ? acc.x : expm1f(acc.x);
        acc.y = acc.y > 0.f ? acc.y : expm1f(acc.y);
        acc.z = acc.z > 0.f ? acc.z : expm1f(acc.z);
        acc.w = acc.w > 0.f ? acc.w : expm1f(acc.w);
    }
    *(float4*)&out_slice[(size_t)node * OUT_STRIDE + lane * 4] = acc;
}

// ---------------- per-layer driver ----------------
static void run_layer(const float* in, int lda,
                      const float* W, const float* al, const float* ar, const float* bias,
                      float* out_slice, int apply_elu,
                      const int* row_start, const int* counts, const int* csr_src,
                      float* feat, float* el, float* er,
                      unsigned short* bt_hi, unsigned short* bt_lo, hipStream_t stream) {
    k_convW<<<256, 256, 0, stream>>>(W, bt_hi, bt_lo);
    k_gemm_mfma<<<(N_NODES + 63) / 64, 512, 0, stream>>>(
        in, lda, bt_hi, bt_lo, feat, N_NODES, al, ar, el, er);
    k_gather<<<(N_NODES * 64 + 255) / 256, 256, 0, stream>>>(
        row_start, counts, csr_src, feat, el, er, bias, out_slice, apply_elu);
}

extern "C" void kernel_launch(void* const* d_in, const int* in_sizes, int n_in,
                              void* d_out, int out_size, void* d_ws, size_t ws_size,
                              hipStream_t stream) {
    const float* x   = (const float*)d_in[0];
    const int*   src = (const int*)d_in[1];
    const int*   dst = (const int*)d_in[2];
    const float* W1  = (const float*)d_in[3];
    const float* al1 = (const float*)d_in[4];
    const float* ar1 = (const float*)d_in[5];
    const float* b1  = (const float*)d_in[6];
    const float* W2  = (const float*)d_in[7];
    const float* al2 = (const float*)d_in[8];
    const float* ar2 = (const float*)d_in[9];
    const float* b2  = (const float*)d_in[10];
    float* out = (float*)d_out;

    // workspace carve-up; guard against undersized ws (fail validation, not the GPU)
    size_t need_bytes = ((size_t)N_NODES * FDIM + 2u * N_NODES * HEADS) * 4u  // feat, el, er
                      + ((size_t)4 * N_NODES + 256 + N_EDGES) * 4u            // csr ints
                      + 2u * 65536u * 2u;                                     // bt_hi/lo
    if (ws_size < need_bytes) return;

    float* ws        = (float*)d_ws;
    float* feat      = ws;                                    // N*256 floats
    float* el        = feat + (size_t)N_NODES * FDIM;         // N*4
    float* er        = el + N_NODES * HEADS;                  // N*4
    int*   counts    = (int*)(er + N_NODES * HEADS);          // N
    int*   excl      = counts + N_NODES;                      // N
    int*   row_start = excl + N_NODES;                        // N
    int*   cursor    = row_start + N_NODES;                   // N
    int*   blocksums = cursor + N_NODES;                      // 256
    int*   csr_src   = blocksums + 256;                       // E
    unsigned short* bt_hi = (unsigned short*)(csr_src + N_EDGES);  // 64K ushort
    unsigned short* bt_lo = bt_hi + 65536;                         // 64K ushort

    // ---- CSR build (shared by both layers) ----
    k_zero_counts<<<(N_NODES + 255) / 256, 256, 0, stream>>>(counts);
    k_hist<<<(N_EDGES + 255) / 256, 256, 0, stream>>>(dst, counts);
    k_scan1<<<NBLK, SCAN_B, 0, stream>>>(counts, excl, blocksums);
    k_scan2<<<1, SCAN_B, 0, stream>>>(blocksums);
    k_scan3<<<(N_NODES + 255) / 256, 256, 0, stream>>>(excl, blocksums, row_start, cursor);
    k_place<<<(N_EDGES + 255) / 256, 256, 0, stream>>>(src, dst, cursor, csr_src);

    // ---- x -> out[:, 0:256] ----
    k_copy_x<<<(N_NODES * 64 + 255) / 256, 256, 0, stream>>>(x, out);

    // ---- layer 1: x -> out[:, 256:512] (ELU) ----
    run_layer(x, FDIM, W1, al1, ar1, b1, out + 256, 1,
              row_start, counts, csr_src, feat, el, er, bt_hi, bt_lo, stream);

    // ---- layer 2: h1 (strided in out) -> out[:, 512:768] ----
    run_layer(out + 256, OUT_STRIDE, W2, al2, ar2, b2, out + 512, 0,
              row_start, counts, csr_src, feat, el, er, bt_hi, bt_lo, stream);
}

// Round 7
// 695.141 us; speedup vs baseline: 1.2424x; 1.0243x over previous
//
#include <hip/hip_runtime.h>
#include <hip/hip_bf16.h>
#include <hip/hip_fp16.h>

#define N_NODES 50000
#define N_EDGES 800000
#define HEADS 4
#define FDIM 256      // HEADS * 64
#define OUT_STRIDE 768
#define SCAN_B 256
#define NBLK ((N_NODES + SCAN_B - 1) / SCAN_B)   // 196 (<= 256, fits single scan block)

typedef __attribute__((ext_vector_type(8))) short short8;   // 8 bf16 = 4 VGPR
typedef __attribute__((ext_vector_type(4))) float f32x4;    // mfma C/D frag

// ---------------- helpers ----------------
__device__ __forceinline__ float lrelu(float v) { return v > 0.f ? v : 0.2f * v; }

__device__ __forceinline__ unsigned short f2bf(float f) {   // RNE fp32 -> bf16 bits
    unsigned u = __float_as_uint(f);
    return (unsigned short)((u + 0x7fffu + ((u >> 16) & 1u)) >> 16);
}
__device__ __forceinline__ float bf2f(unsigned short s) {
    return __uint_as_float(((unsigned)s) << 16);
}

// ---------------- W -> B^T split-bf16 (hi/lo), once per layer ----------------
// bt[col*256 + k] = split(W[k*256 + col]); b-frag reads are then 16B contiguous.
__global__ void k_convW(const float* __restrict__ W,
                        unsigned short* __restrict__ bt_hi,
                        unsigned short* __restrict__ bt_lo) {
    int t = blockIdx.x * blockDim.x + threadIdx.x;   // 65536
    int k = t >> 8, col = t & 255;                   // read coalesced over col
    float f = W[k * 256 + col];
    unsigned short h = f2bf(f);
    bt_hi[(size_t)col * 256 + k] = h;
    bt_lo[(size_t)col * 256 + k] = f2bf(f - bf2f(h));
}

// ---------------- split-bf16 MFMA GEMM + fused el/er epilogue ----------------
// feat(fp16)[M x 256] = A[M x 256 (lda)] @ B[256 x 256], fp32 accum via 3-product
// split: a*b ~= ahi*bhi + alo*bhi + ahi*blo  (lo*lo ~2^-16 rel, dropped).
// feat is consumed ONLY by k_gather -> store fp16 (halves gather traffic; err 2^-11).
// Block: 512 thr = 8 waves; tile 64 rows x 256 cols (full N -> A read once).
// Wave w: rows (w>>2)*32 (2 frags), cols (w&3)*64 (4 frags) = 1 head.
// A: whole K in LDS as hi/lo bf16, XOR-swizzled 16B chunks; ONE barrier total.
// B: B^T hi/lo bf16 direct from global (256KB, L2-resident). No LDS.
// Layer 1 also copies x rows into out[:,0:256] during staging (replaces k_copy_x).
// mfma_f32_16x16x32_bf16 layouts (verified, learn_hip m89/m91/m97):
//   A-frag: row=lane&15, k=8*(lane>>4)+i ; B-frag: col=lane&15 (B^T row), same k
//   C/D:    col=lane&15, row=(lane>>4)*4+reg
__device__ __forceinline__ int a_idx(int row, int cq) {      // ushort index in As
    return row * 256 + ((cq ^ (row & 31)) << 3);             // 16B-chunk XOR swizzle
}

__global__ __launch_bounds__(512) void k_gemm_mfma(
        const float* __restrict__ A, int lda,
        const unsigned short* __restrict__ bt_hi, const unsigned short* __restrict__ bt_lo,
        __half* __restrict__ feat, int M,
        const float* __restrict__ al, const float* __restrict__ ar,
        float* __restrict__ el, float* __restrict__ er,
        float* __restrict__ xcopy) {          // if non-null: copy A rows -> xcopy[row*768+..]
    __shared__ __align__(16) unsigned short As_hi[64 * 256];   // 32 KB
    __shared__ __align__(16) unsigned short As_lo[64 * 256];   // 32 KB
    const int tid = threadIdx.x;
    const int brow = blockIdx.x * 64;

    // ---- stage A rows [brow..brow+63] x K=256 as split bf16 ----
    {
        const int row = tid >> 3;          // 0..63
        const int seg = tid & 7;           // 0..7 -> cols seg*32..+31
        const int grow = brow + row;
        const bool valid = grow < M;
        const float* ap = A + (size_t)grow * lda + seg * 32;
#pragma unroll
        for (int c = 0; c < 4; ++c) {
            float fv[8];
            if (valid) {
                float4 f0 = *(const float4*)(ap + c * 8);
                float4 f1 = *(const float4*)(ap + c * 8 + 4);
                fv[0]=f0.x; fv[1]=f0.y; fv[2]=f0.z; fv[3]=f0.w;
                fv[4]=f1.x; fv[5]=f1.y; fv[6]=f1.z; fv[7]=f1.w;
                if (xcopy) {   // fused x -> out[:,0:256] (wave-uniform branch)
                    float* xp = &xcopy[(size_t)grow * OUT_STRIDE + seg * 32 + c * 8];
                    *(float4*)xp = f0;
                    *(float4*)(xp + 4) = f1;
                }
            } else {
#pragma unroll
                for (int j = 0; j < 8; ++j) fv[j] = 0.f;
            }
            short8 vh, vl;
#pragma unroll
            for (int j = 0; j < 8; ++j) {
                unsigned short h = f2bf(fv[j]);
                vh[j] = (short)h;
                vl[j] = (short)f2bf(fv[j] - bf2f(h));
            }
            int idx = a_idx(row, seg * 4 + c);
            *(short8*)&As_hi[idx] = vh;
            *(short8*)&As_lo[idx] = vl;
        }
    }
    __syncthreads();

    // ---- K loop: 8 steps of K=32, no barriers ----
    const int lane = tid & 63;
    const int w = tid >> 6;
    const int wr = w >> 2;            // 0..1 -> rows wr*32
    const int wc = w & 3;             // 0..3 -> cols wc*64 (= head wc)
    const int ln15 = lane & 15;
    const int kg = lane >> 4;         // 0..3
    f32x4 acc[2][4] = {};

#pragma unroll 2
    for (int ks = 0; ks < 8; ++ks) {
        short8 ah[2], am[2];
#pragma unroll
        for (int rf = 0; rf < 2; ++rf) {
            int idx = a_idx(wr * 32 + rf * 16 + ln15, ks * 4 + kg);
            ah[rf] = *(const short8*)&As_hi[idx];
            am[rf] = *(const short8*)&As_lo[idx];
        }
#pragma unroll
        for (int cf = 0; cf < 4; ++cf) {
            size_t boff = (size_t)(wc * 64 + cf * 16 + ln15) * 256 + ks * 32 + kg * 8;
            short8 bh = *(const short8*)&bt_hi[boff];
            short8 bl = *(const short8*)&bt_lo[boff];
#pragma unroll
            for (int rf = 0; rf < 2; ++rf) {
                acc[rf][cf] = __builtin_amdgcn_mfma_f32_16x16x32_bf16(ah[rf], bh, acc[rf][cf], 0, 0, 0);
                acc[rf][cf] = __builtin_amdgcn_mfma_f32_16x16x32_bf16(am[rf], bh, acc[rf][cf], 0, 0, 0);
                acc[rf][cf] = __builtin_amdgcn_mfma_f32_16x16x32_bf16(ah[rf], bl, acc[rf][cf], 0, 0, 0);
            }
        }
    }

    // ---- epilogue: store feat (fp16) + fused el/er ----
#pragma unroll
    for (int rf = 0; rf < 2; ++rf) {
        float pel[4] = {0.f, 0.f, 0.f, 0.f};
        float per[4] = {0.f, 0.f, 0.f, 0.f};
#pragma unroll
        for (int cf = 0; cf < 4; ++cf) {
            int gcol = wc * 64 + cf * 16 + ln15;
            float alv = al[gcol], arv = ar[gcol];
#pragma unroll
            for (int reg = 0; reg < 4; ++reg) {
                float v = acc[rf][cf][reg];
                int gr = brow + wr * 32 + rf * 16 + kg * 4 + reg;
                if (gr < M) feat[(size_t)gr * 256 + gcol] = __float2half(v);
                pel[reg] += v * alv;
                per[reg] += v * arv;
            }
        }
        // reduce across the 16 lanes (cols) sharing each row
#pragma unroll
        for (int reg = 0; reg < 4; ++reg) {
#pragma unroll
            for (int off = 1; off <= 8; off <<= 1) {
                pel[reg] += __shfl_xor(pel[reg], off, 64);
                per[reg] += __shfl_xor(per[reg], off, 64);
            }
        }
        if (ln15 == 0) {
#pragma unroll
            for (int reg = 0; reg < 4; ++reg) {
                int gr = brow + wr * 32 + rf * 16 + kg * 4 + reg;
                if (gr < M) {
                    el[gr * HEADS + wc] = pel[reg];
                    er[gr * HEADS + wc] = per[reg];
                }
            }
        }
    }
}

// ---------------- CSR build (once per launch; shared by both layers) ----------------
__global__ void k_zero_counts(int* __restrict__ counts) {
    int i = blockIdx.x * blockDim.x + threadIdx.x;
    if (i < N_NODES) counts[i] = 0;
}
__global__ void k_hist(const int* __restrict__ dst, int* __restrict__ counts) {
    int e = blockIdx.x * blockDim.x + threadIdx.x;
    if (e < N_EDGES) atomicAdd(&counts[dst[e]], 1);
}
__global__ void k_scan1(const int* __restrict__ counts, int* __restrict__ excl,
                        int* __restrict__ blocksums) {
    __shared__ int s[SCAN_B];
    int tid = threadIdx.x;
    int i = blockIdx.x * SCAN_B + tid;
    int v = (i < N_NODES) ? counts[i] : 0;
    s[tid] = v;
    __syncthreads();
    for (int off = 1; off < SCAN_B; off <<= 1) {
        int t = (tid >= off) ? s[tid - off] : 0;
        __syncthreads();
        s[tid] += t;
        __syncthreads();
    }
    if (i < N_NODES) excl[i] = s[tid] - v;
    if (tid == SCAN_B - 1) blocksums[blockIdx.x] = s[tid];
}
__global__ void k_scan2(int* __restrict__ blocksums) {   // single block; NBLK <= 256
    __shared__ int s[SCAN_B];
    int tid = threadIdx.x;
    int v = (tid < NBLK) ? blocksums[tid] : 0;
    s[tid] = v;
    __syncthreads();
    for (int off = 1; off < SCAN_B; off <<= 1) {
        int t = (tid >= off) ? s[tid - off] : 0;
        __syncthreads();
        s[tid] += t;
        __syncthreads();
    }
    if (tid < NBLK) blocksums[tid] = s[tid] - v;   // exclusive
}
__global__ void k_scan3(const int* __restrict__ excl, const int* __restrict__ blocksums,
                        int* __restrict__ row_start, int* __restrict__ cursor) {
    int i = blockIdx.x * blockDim.x + threadIdx.x;
    if (i >= N_NODES) return;
    int r = excl[i] + blocksums[i >> 8];
    row_start[i] = r;
    cursor[i] = r;
}
__global__ void k_place(const int* __restrict__ src, const int* __restrict__ dst,
                        int* __restrict__ cursor, int* __restrict__ csr_src) {
    int e = blockIdx.x * blockDim.x + threadIdx.x;
    if (e >= N_EDGES) return;
    int pos = atomicAdd(&cursor[dst[e]], 1);
    csr_src[pos] = src[e];
}

// ---------------- fused edge softmax + aggregate: one wave per dst node ----------------
// Single pass, online softmax. feat is fp16: 8B/lane loads (halves the BW floor).
__global__ void k_gather(const int* __restrict__ row_start, const int* __restrict__ counts,
                         const int* __restrict__ csr_src,
                         const __half* __restrict__ feat,
                         const float* __restrict__ el, const float* __restrict__ er,
                         const float* __restrict__ bias,
                         float* __restrict__ out_slice, int apply_elu) {
    int gtid = blockIdx.x * blockDim.x + threadIdx.x;
    int node = gtid >> 6;
    if (node >= N_NODES) return;
    int lane = threadIdx.x & 63;
    int h = lane >> 4;                           // head of this lane's 4 channels
    float4 bv = *(const float4*)&bias[lane * 4];
    int start = row_start[node];
    int cnt = counts[node];
    float4 acc = make_float4(0.f, 0.f, 0.f, 0.f);
    if (cnt > 0) {
        float erd = er[node * HEADS + h];
        float m = -1e30f, denom = 0.f;
        for (int i = 0; i < cnt; ++i) {
            int s = csr_src[start + i];
            float v = lrelu(el[s * HEADS + h] + erd);
            float mn = fmaxf(m, v);
            float scale = __expf(m - mn);        // 1 when no new max
            float ex = __expf(v - mn);
            m = mn;
            denom = denom * scale + ex;
            uint2 raw = *(const uint2*)&feat[(size_t)s * FDIM + lane * 4];
            __half2 p0 = *(__half2*)&raw.x;
            __half2 p1 = *(__half2*)&raw.y;
            float2 f0 = __half22float2(p0);
            float2 f1 = __half22float2(p1);
            acc.x = acc.x * scale + ex * f0.x;
            acc.y = acc.y * scale + ex * f0.y;
            acc.z = acc.z * scale + ex * f1.x;
            acc.w = acc.w * scale + ex * f1.y;
        }
        float inv = 1.f / denom;
        acc.x = acc.x * inv + bv.x; acc.y = acc.y * inv + bv.y;
        acc.z = acc.z * inv + bv.z; acc.w = acc.w * inv + bv.w;
    } else {
        acc = bv;   // empty segment: message sum is 0, out = bias
    }
    if (apply_elu) {
        acc.x = acc.x > 0.f ? acc.x : expm1f(acc.x);
        acc.y = acc.y > 0.f ? acc.y : expm1f(acc.y);
        acc.z = acc.z > 0.f ? acc.z : expm1f(acc.z);
        acc.w = acc.w > 0.f ? acc.w : expm1f(acc.w);
    }
    *(float4*)&out_slice[(size_t)node * OUT_STRIDE + lane * 4] = acc;
}

// ---------------- per-layer driver ----------------
static void run_layer(const float* in, int lda,
                      const float* W, const float* al, const float* ar, const float* bias,
                      float* out_slice, int apply_elu, float* xcopy,
                      const int* row_start, const int* counts, const int* csr_src,
                      __half* feat, float* el, float* er,
                      unsigned short* bt_hi, unsigned short* bt_lo, hipStream_t stream) {
    k_convW<<<256, 256, 0, stream>>>(W, bt_hi, bt_lo);
    k_gemm_mfma<<<(N_NODES + 63) / 64, 512, 0, stream>>>(
        in, lda, bt_hi, bt_lo, feat, N_NODES, al, ar, el, er, xcopy);
    k_gather<<<(N_NODES * 64 + 255) / 256, 256, 0, stream>>>(
        row_start, counts, csr_src, feat, el, er, bias, out_slice, apply_elu);
}

extern "C" void kernel_launch(void* const* d_in, const int* in_sizes, int n_in,
                              void* d_out, int out_size, void* d_ws, size_t ws_size,
                              hipStream_t stream) {
    const float* x   = (const float*)d_in[0];
    const int*   src = (const int*)d_in[1];
    const int*   dst = (const int*)d_in[2];
    const float* W1  = (const float*)d_in[3];
    const float* al1 = (const float*)d_in[4];
    const float* ar1 = (const float*)d_in[5];
    const float* b1  = (const float*)d_in[6];
    const float* W2  = (const float*)d_in[7];
    const float* al2 = (const float*)d_in[8];
    const float* ar2 = (const float*)d_in[9];
    const float* b2  = (const float*)d_in[10];
    float* out = (float*)d_out;

    // workspace carve-up; guard against undersized ws (fail validation, not the GPU)
    size_t need_bytes = ((size_t)N_NODES * 128 + 2u * N_NODES * HEADS) * 4u   // feat(fp16), el, er
                      + ((size_t)4 * N_NODES + 256 + N_EDGES) * 4u            // csr ints
                      + 2u * 65536u * 2u;                                     // bt_hi/lo
    if (ws_size < need_bytes) return;

    float* ws        = (float*)d_ws;
    __half* feat     = (__half*)ws;                           // N*256 halves = N*128 floats
    float* el        = ws + (size_t)N_NODES * 128;            // N*4
    float* er        = el + N_NODES * HEADS;                  // N*4
    int*   counts    = (int*)(er + N_NODES * HEADS);          // N
    int*   excl      = counts + N_NODES;                      // N
    int*   row_start = excl + N_NODES;                        // N
    int*   cursor    = row_start + N_NODES;                   // N
    int*   blocksums = cursor + N_NODES;                      // 256
    int*   csr_src   = blocksums + 256;                       // E
    unsigned short* bt_hi = (unsigned short*)(csr_src + N_EDGES);  // 64K ushort
    unsigned short* bt_lo = bt_hi + 65536;                         // 64K ushort

    // ---- CSR build (shared by both layers) ----
    k_zero_counts<<<(N_NODES + 255) / 256, 256, 0, stream>>>(counts);
    k_hist<<<(N_EDGES + 255) / 256, 256, 0, stream>>>(dst, counts);
    k_scan1<<<NBLK, SCAN_B, 0, stream>>>(counts, excl, blocksums);
    k_scan2<<<1, SCAN_B, 0, stream>>>(blocksums);
    k_scan3<<<(N_NODES + 255) / 256, 256, 0, stream>>>(excl, blocksums, row_start, cursor);
    k_place<<<(N_EDGES + 255) / 256, 256, 0, stream>>>(src, dst, cursor, csr_src);

    // ---- layer 1: x -> out[:, 256:512] (ELU); also copies x -> out[:, 0:256] ----
    run_layer(x, FDIM, W1, al1, ar1, b1, out + 256, 1, out,
              row_start, counts, csr_src, feat, el, er, bt_hi, bt_lo, stream);

    // ---- layer 2: h1 (strided in out) -> out[:, 512:768] ----
    run_layer(out + 256, OUT_STRIDE, W2, al2, ar2, b2, out + 512, 0, nullptr,
              row_start, counts, csr_src, feat, el, er, bt_hi, bt_lo, stream);
}